// Round 1
// baseline (106.085 us; speedup 1.0000x reference)
//
#include <hip/hip_runtime.h>

#define FRAME 160
#define ORDER 12
#define NFRAMES (4096 * 15)
#define EPL 10            // elements per sub-lane (16 lanes per frame-pair)
#define ROWP 174          // 12 front pad + 160 + 1 zero tail + 1 align pad (16B row stride)

typedef float v2f __attribute__((ext_vector_type(2)));

__device__ __forceinline__ v2f pkfma(v2f a, v2f b, v2f c) {
    return __builtin_elementwise_fma(a, b, c);
}
__device__ __forceinline__ v2f splat2(float v) { v2f r; r.x = v; r.y = v; return r; }

template<int CTRL>
__device__ __forceinline__ float dppf(float v) {
    return __int_as_float(__builtin_amdgcn_update_dpp(
        0, __float_as_int(v), CTRL, 0xF, 0xF, true));
}

// Sum across each 16-lane row, pure-VALU DPP; bit-identical in all 16 lanes.
__device__ __forceinline__ float rowsum16(float v) {
    v += dppf<0xB1>(v);    // quad_perm [1,0,3,2]  : lane ^= 1
    v += dppf<0x4E>(v);    // quad_perm [2,3,0,1]  : lane ^= 2
    v += dppf<0x140>(v);   // row_mirror
    v += dppf<0x141>(v);   // row_half_mirror
    return v;
}
__device__ __forceinline__ v2f rowsum16v(v2f v) {  // two independent chains (ILP x2)
    v2f r; r.x = rowsum16(v.x); r.y = rowsum16(v.y); return r;
}

// min 4 waves/EU => VGPR cap 128 => 16 waves/CU. Live-set estimate ~90 regs
// (FIR phase: Xw 44 + ak 26 + addr/acc ~20), so no spills expected.
__global__ __launch_bounds__(256, 4) void ResidualEmbedding_70798240907390_kernel(
    const int* __restrict__ bits, const float* __restrict__ pcm,
    const float* __restrict__ alpha_p, float* __restrict__ out)
{
    const int tid  = threadIdx.x;
    const int wave = tid >> 6;
    const int lane = tid & 63;
    const int g    = lane >> 4;          // frame-PAIR group within wave
    const int s    = lane & 15;
    const int wf0  = (blockIdx.x * 4 + wave) * 8;   // 8 frames per wave
    const int fA   = wf0 + 2 * g;
    const int fB   = fA + 1;

    // All LDS is wave-local ([wave] major index) -> kernel is barrier-free.
    // Same-wave DS ops are processed in order by the LDS pipe; wave_barrier
    // only pins the compile-time schedule.
    __shared__ __align__(16) v2f s_x[4][4][ROWP];
    __shared__ v2f  s_a[4][4][16];

    // Zero front pads (12 pairs x 4 rows) and tail pad (1 pair x 4 rows).
    if (lane < 48) { int gr = lane / 12, j = lane % 12; s_x[wave][gr][j] = splat2(0.f); }
    if (lane < 4)  s_x[wave][lane][172] = splat2(0.f);

    // Stage: coalesced float4 per frame, written pair-interleaved as 2x b128.
    {
        const float* pAg = pcm + (size_t)fA * FRAME;
        const float* pBg = pcm + (size_t)fB * FRAME;
#pragma unroll
        for (int c = 0; c < 3; ++c) {
            int p = 4 * s + 64 * c;
            if (p < FRAME) {
                float4 a4 = *(const float4*)(pAg + p);
                float4 b4 = *(const float4*)(pBg + p);
                float4* dst = (float4*)&s_x[wave][g][12 + p];   // 16B aligned
                dst[0] = make_float4(a4.x, b4.x, a4.y, b4.y);
                dst[1] = make_float4(a4.z, b4.z, a4.w, b4.w);
            }
        }
    }
    __builtin_amdgcn_wave_barrier();

    const v2f* X = &s_x[wave][g][12];    // X[p] = {xA[p], xB[p]}, p in [-12, 160]
    const int p0 = s * EPL;

    // Windowed products; window computed per-lane (removes s_win + the block
    // barrier). b[p]=xw[p], f[p]=xw[p+1]; position 159 zero invariant
    // (X[160] = 0 via tail pad, so the p=160 product is 0 regardless of w).
    v2f F[EPL], B[EPL];
    {
        const float kW = 6.2831853071795864769f / 159.0f;
        v2f pr[EPL + 1];
#pragma unroll
        for (int j = 0; j <= EPL; ++j) {
            float w = 0.5f - 0.5f * __cosf(kW * (float)(p0 + j));
            pr[j] = X[p0 + j] * w;
        }
#pragma unroll
        for (int t = 0; t < EPL; ++t) { F[t] = pr[t + 1]; B[t] = pr[t]; }
    }
    if (s == 15) B[EPL - 1] = splat2(0.f);
    v2f dpF = splat2(0.f), dpB = splat2(0.f);
#pragma unroll
    for (int t = 0; t < EPL; ++t) {
        dpF = pkfma(F[t], F[t], dpF);
        dpB = pkfma(B[t], B[t], dpB);
    }
    v2f den = rowsum16v(dpF + dpB);

    v2f a  = (s == 0) ? splat2(1.f) : splat2(0.f);
    v2f ar = (s == 1) ? splat2(1.f) : splat2(0.f);
    v2f cp = splat2(0.f), dsc = splat2(0.f);

#pragma unroll
    for (int i = 0; i < ORDER; ++i) {
        v2f q0 = splat2(0.f), q1 = splat2(0.f);
#pragma unroll
        for (int t = 0; t < EPL; t += 2) {
            q0 = pkfma(F[t],     B[t],     q0);
            q1 = pkfma(F[t + 1], B[t + 1], q1);
        }
        v2f num = rowsum16v(q0 + q1);
        if (i > 0) den = dsc - rowsum16v(cp);
        v2f r;
        r.x = -2.0f * num.x * __builtin_amdgcn_rcpf(den.x);
        r.y = -2.0f * num.y * __builtin_amdgcn_rcpf(den.y);

        // a[:i+2] += r*a[:i+2][::-1]:  a'=a+r*ar ; ar'=(ar+r*a)>>1 lane
        v2f an  = pkfma(r, ar, a);
        v2f arn = pkfma(r, a, ar);
        a = an;
        ar.x = dppf<0x111>(arn.x);       // row_shr:1, lane0 <- 0
        ar.y = dppf<0x111>(arn.y);

        // In-place lattice update (each pk op serves BOTH frames).
#pragma unroll
        for (int t = 0; t < EPL; ++t) {
            v2f fo = F[t];
            F[t] = pkfma(r, B[t], fo);
            B[t] = pkfma(r, fo, B[t]);
        }

        const int pe = 158 - i;          // compile-time (full unroll)
        const int SL = pe / EPL, SS = pe % EPL;
        v2f fe = (s == 0)  ? F[0]  : splat2(0.f);
        v2f be = (s == SL) ? B[SS] : splat2(0.f);
        cp  = pkfma(fe, fe, be * be);
        dsc = pkfma(-(r * r), den, den); // (1-r^2)*den

        // f = f'[1:]  (row_shl:1; lane15 -> 0 keeps invariant)
        v2f up;
        up.x = dppf<0x101>(F[0].x);
        up.y = dppf<0x101>(F[0].y);
#pragma unroll
        for (int t = 0; t < EPL - 1; ++t) F[t] = F[t + 1];
        F[EPL - 1] = up;
        if (s == SL) B[SS] = splat2(0.f);
    }

    // Broadcast packed a[0..12] within the group via same-wave LDS bounce.
    // No block barrier needed: writer and readers are the same wave, and the
    // LDS pipe services a wave's DS ops in program order.
    s_a[wave][g][s] = a;
    __builtin_amdgcn_wave_barrier();
    v2f ak[ORDER + 1];
#pragma unroll
    for (int k = 0; k <= ORDER; ++k) ak[k] = s_a[wave][g][k];

    // FIR window straight from pair-interleaved LDS (front pad = zero history).
    v2f Xw[EPL + ORDER];
#pragma unroll
    for (int j = 0; j < EPL + ORDER; ++j) Xw[j] = X[p0 - ORDER + j];

    const float alpha = alpha_p[0];
    v2f ac;
    ac.x = alpha * (2.0f * (float)bits[fA] - 1.0f);
    ac.y = alpha * (2.0f * (float)bits[fB] - 1.0f);

    float* oA = out + (size_t)fA * FRAME + p0;
    float* oB = out + (size_t)fB * FRAME + p0;
#pragma unroll
    for (int t = 0; t < EPL; t += 2) {
        v2f acc0 = splat2(0.f), acc1 = splat2(0.f);
#pragma unroll
        for (int k = 0; k <= ORDER; ++k) {
            acc0 = pkfma(ak[k], Xw[ORDER + t - k],     acc0);
            acc1 = pkfma(ak[k], Xw[ORDER + t + 1 - k], acc1);
        }
        v2f r0 = pkfma(ac, acc0, Xw[ORDER + t]);
        v2f r1 = pkfma(ac, acc1, Xw[ORDER + t + 1]);
        *(float2*)(oA + t) = make_float2(r0.x, r1.x);
        *(float2*)(oB + t) = make_float2(r0.y, r1.y);
    }
}

extern "C" void kernel_launch(void* const* d_in, const int* in_sizes, int n_in,
                              void* d_out, int out_size, void* d_ws, size_t ws_size,
                              hipStream_t stream) {
    const int*   bits  = (const int*)d_in[0];
    const float* pcm   = (const float*)d_in[1];
    const float* alpha = (const float*)d_in[2];
    float*       out   = (float*)d_out;

    // 61440 frames; 32 per block (4 waves x 4 groups x 2 packed frames).
    dim3 grid(NFRAMES / 32), block(256);
    hipLaunchKernelGGL(ResidualEmbedding_70798240907390_kernel, grid, block, 0, stream,
                       bits, pcm, alpha, out);
}

// Round 2
// 105.940 us; speedup vs baseline: 1.0014x; 1.0014x over previous
//
#include <hip/hip_runtime.h>

#define FRAME 160
#define ORDER 12
#define NFRAMES (4096 * 15)
#define EPL 10            // elements per sub-lane (16 lanes per frame-pair)
#define ROWP 174          // 12 front pad + 160 + 1 zero tail + 1 align pad (16B row stride)

typedef float v2f __attribute__((ext_vector_type(2)));

__device__ __forceinline__ v2f pkfma(v2f a, v2f b, v2f c) {
    return __builtin_elementwise_fma(a, b, c);
}
__device__ __forceinline__ v2f splat2(float v) { v2f r; r.x = v; r.y = v; return r; }

template<int CTRL>
__device__ __forceinline__ float dppf(float v) {
    return __int_as_float(__builtin_amdgcn_update_dpp(
        0, __float_as_int(v), CTRL, 0xF, 0xF, true));
}

// Sum across each 16-lane row, pure-VALU DPP; bit-identical in all 16 lanes.
__device__ __forceinline__ float rowsum16(float v) {
    v += dppf<0xB1>(v);    // quad_perm [1,0,3,2]  : lane ^= 1
    v += dppf<0x4E>(v);    // quad_perm [2,3,0,1]  : lane ^= 2
    v += dppf<0x140>(v);   // row_mirror
    v += dppf<0x141>(v);   // row_half_mirror
    return v;
}
__device__ __forceinline__ v2f rowsum16v(v2f v) {  // two independent chains (ILP x2)
    v2f r; r.x = rowsum16(v.x); r.y = rowsum16(v.y); return r;
}

// Single-wave blocks: wave-granular backfill (retiring wave's slot refills
// immediately; fresh wave's global-load burst hides under neighbors' Burg
// compute). Kernel is barrier-free; all LDS is wave-local.
__global__ __launch_bounds__(64, 4) void ResidualEmbedding_70798240907390_kernel(
    const int* __restrict__ bits, const float* __restrict__ pcm,
    const float* __restrict__ alpha_p, float* __restrict__ out)
{
    const int lane = threadIdx.x;        // block == one wave
    const int g    = lane >> 4;          // frame-PAIR group within wave
    const int s    = lane & 15;
    const int wf0  = blockIdx.x * 8;     // 8 frames per wave
    const int fA   = wf0 + 2 * g;
    const int fB   = fA + 1;

    __shared__ __align__(16) v2f s_x[4][ROWP];
    __shared__ float s_win[161];
    __shared__ v2f  s_a[4][16];

    // Hann window per wave (no block barrier needed: same-wave LDS ordering).
    // ~3 cos/thread instead of 11 (quarter-rate transcendental).
    {
        const float kW = 6.2831853071795864769f / 159.0f;
        for (int j = lane; j < 161; j += 64) {
            s_win[j] = (j < 160) ? 0.5f - 0.5f * __cosf(kW * (float)j) : 0.0f;
        }
    }
    // Zero front pads (12 pairs x 4 rows) and tail pad (1 pair x 4 rows).
    if (lane < 48) { int gr = lane / 12, j = lane % 12; s_x[gr][j] = splat2(0.f); }
    if (lane < 4)  s_x[lane][172] = splat2(0.f);

    // Stage: coalesced float4 per frame, written pair-interleaved as 2x b128.
    {
        const float* pAg = pcm + (size_t)fA * FRAME;
        const float* pBg = pcm + (size_t)fB * FRAME;
#pragma unroll
        for (int c = 0; c < 3; ++c) {
            int p = 4 * s + 64 * c;
            if (p < FRAME) {
                float4 a4 = *(const float4*)(pAg + p);
                float4 b4 = *(const float4*)(pBg + p);
                float4* dst = (float4*)&s_x[g][12 + p];   // 16B aligned
                dst[0] = make_float4(a4.x, b4.x, a4.y, b4.y);
                dst[1] = make_float4(a4.z, b4.z, a4.w, b4.w);
            }
        }
    }
    __builtin_amdgcn_wave_barrier();

    const v2f* X = &s_x[g][12];          // X[p] = {xA[p], xB[p]}, p in [-12, 160]
    const int p0 = s * EPL;

    // Windowed products; b[p]=xw[p], f[p]=xw[p+1]; position 159 zero invariant
    // (X[160] = 0 via tail pad AND win[160] = 0).
    v2f F[EPL], B[EPL];
    {
        v2f pr[EPL + 1];
#pragma unroll
        for (int j = 0; j <= EPL; ++j)
            pr[j] = X[p0 + j] * s_win[p0 + j];
#pragma unroll
        for (int t = 0; t < EPL; ++t) { F[t] = pr[t + 1]; B[t] = pr[t]; }
    }
    if (s == 15) B[EPL - 1] = splat2(0.f);
    v2f dpF = splat2(0.f), dpB = splat2(0.f);
#pragma unroll
    for (int t = 0; t < EPL; ++t) {
        dpF = pkfma(F[t], F[t], dpF);
        dpB = pkfma(B[t], B[t], dpB);
    }
    v2f den = rowsum16v(dpF + dpB);

    v2f a  = (s == 0) ? splat2(1.f) : splat2(0.f);
    v2f ar = (s == 1) ? splat2(1.f) : splat2(0.f);
    v2f cp = splat2(0.f), dsc = splat2(0.f);

#pragma unroll
    for (int i = 0; i < ORDER; ++i) {
        v2f q0 = splat2(0.f), q1 = splat2(0.f);
#pragma unroll
        for (int t = 0; t < EPL; t += 2) {
            q0 = pkfma(F[t],     B[t],     q0);
            q1 = pkfma(F[t + 1], B[t + 1], q1);
        }
        v2f num = rowsum16v(q0 + q1);
        if (i > 0) den = dsc - rowsum16v(cp);
        v2f r;
        r.x = -2.0f * num.x * __builtin_amdgcn_rcpf(den.x);
        r.y = -2.0f * num.y * __builtin_amdgcn_rcpf(den.y);

        // a[:i+2] += r*a[:i+2][::-1]:  a'=a+r*ar ; ar'=(ar+r*a)>>1 lane
        v2f an  = pkfma(r, ar, a);
        v2f arn = pkfma(r, a, ar);
        a = an;
        ar.x = dppf<0x111>(arn.x);       // row_shr:1, lane0 <- 0
        ar.y = dppf<0x111>(arn.y);

        // In-place lattice update (each pk op serves BOTH frames).
#pragma unroll
        for (int t = 0; t < EPL; ++t) {
            v2f fo = F[t];
            F[t] = pkfma(r, B[t], fo);
            B[t] = pkfma(r, fo, B[t]);
        }

        const int pe = 158 - i;          // compile-time (full unroll)
        const int SL = pe / EPL, SS = pe % EPL;
        v2f fe = (s == 0)  ? F[0]  : splat2(0.f);
        v2f be = (s == SL) ? B[SS] : splat2(0.f);
        cp  = pkfma(fe, fe, be * be);
        dsc = pkfma(-(r * r), den, den); // (1-r^2)*den

        // f = f'[1:]  (row_shl:1; lane15 -> 0 keeps invariant)
        v2f up;
        up.x = dppf<0x101>(F[0].x);
        up.y = dppf<0x101>(F[0].y);
#pragma unroll
        for (int t = 0; t < EPL - 1; ++t) F[t] = F[t + 1];
        F[EPL - 1] = up;
        if (s == SL) B[SS] = splat2(0.f);
    }

    // Broadcast packed a[0..12] within the group via same-wave LDS bounce.
    s_a[g][s] = a;
    __builtin_amdgcn_wave_barrier();
    v2f ak[ORDER + 1];
#pragma unroll
    for (int k = 0; k <= ORDER; ++k) ak[k] = s_a[g][k];

    // FIR window straight from pair-interleaved LDS (front pad = zero history).
    v2f Xw[EPL + ORDER];
#pragma unroll
    for (int j = 0; j < EPL + ORDER; ++j) Xw[j] = X[p0 - ORDER + j];

    const float alpha = alpha_p[0];
    v2f ac;
    ac.x = alpha * (2.0f * (float)bits[fA] - 1.0f);
    ac.y = alpha * (2.0f * (float)bits[fB] - 1.0f);

    float* oA = out + (size_t)fA * FRAME + p0;
    float* oB = out + (size_t)fB * FRAME + p0;
#pragma unroll
    for (int t = 0; t < EPL; t += 2) {
        v2f acc0 = splat2(0.f), acc1 = splat2(0.f);
#pragma unroll
        for (int k = 0; k <= ORDER; ++k) {
            acc0 = pkfma(ak[k], Xw[ORDER + t - k],     acc0);
            acc1 = pkfma(ak[k], Xw[ORDER + t + 1 - k], acc1);
        }
        v2f r0 = pkfma(ac, acc0, Xw[ORDER + t]);
        v2f r1 = pkfma(ac, acc1, Xw[ORDER + t + 1]);
        *(float2*)(oA + t) = make_float2(r0.x, r1.x);
        *(float2*)(oB + t) = make_float2(r0.y, r1.y);
    }
}

extern "C" void kernel_launch(void* const* d_in, const int* in_sizes, int n_in,
                              void* d_out, int out_size, void* d_ws, size_t ws_size,
                              hipStream_t stream) {
    const int*   bits  = (const int*)d_in[0];
    const float* pcm   = (const float*)d_in[1];
    const float* alpha = (const float*)d_in[2];
    float*       out   = (float*)d_out;

    // 61440 frames; 8 per single-wave block (4 groups x 2 packed frames).
    dim3 grid(NFRAMES / 8), block(64);
    hipLaunchKernelGGL(ResidualEmbedding_70798240907390_kernel, grid, block, 0, stream,
                       bits, pcm, alpha, out);
}

// Round 3
// 104.263 us; speedup vs baseline: 1.0175x; 1.0161x over previous
//
#include <hip/hip_runtime.h>

#define FRAME 160
#define ORDER 12
#define NFRAMES (4096 * 15)
#define EPL 10            // elements per sub-lane (16 lanes per frame-pair)
#define ROWP 174          // 12 front pad + 160 + 1 zero tail + 1 align pad (16B row stride)

typedef float v2f __attribute__((ext_vector_type(2)));

__device__ __forceinline__ v2f pkfma(v2f a, v2f b, v2f c) {
    return __builtin_elementwise_fma(a, b, c);
}
__device__ __forceinline__ v2f splat2(float v) { v2f r; r.x = v; r.y = v; return r; }

template<int CTRL>
__device__ __forceinline__ float dppf(float v) {
    return __int_as_float(__builtin_amdgcn_update_dpp(
        0, __float_as_int(v), CTRL, 0xF, 0xF, true));
}

// Sum across each 16-lane row, pure-VALU DPP; bit-identical in all 16 lanes.
__device__ __forceinline__ float rowsum16(float v) {
    v += dppf<0xB1>(v);    // quad_perm [1,0,3,2]  : lane ^= 1
    v += dppf<0x4E>(v);    // quad_perm [2,3,0,1]  : lane ^= 2
    v += dppf<0x140>(v);   // row_mirror
    v += dppf<0x141>(v);   // row_half_mirror
    return v;
}
__device__ __forceinline__ v2f rowsum16v(v2f v) {  // two independent chains (ILP x2)
    v2f r; r.x = rowsum16(v.x); r.y = rowsum16(v.y); return r;
}

// 2-wave blocks: escapes the ~16-workgroup/CU cap that limited 1-wave blocks
// to ~16 waves/CU. LDS/block ~13 KB -> 12 blocks/CU -> 24 waves/CU (75%).
// All LDS remains wave-local ([wave] major index) -> still barrier-free.
// __launch_bounds__(128, 8): VGPR cap 64 (compiler currently at 40).
__global__ __launch_bounds__(128, 8) void ResidualEmbedding_70798240907390_kernel(
    const int* __restrict__ bits, const float* __restrict__ pcm,
    const float* __restrict__ alpha_p, float* __restrict__ out)
{
    const int tid  = threadIdx.x;
    const int wave = tid >> 6;
    const int lane = tid & 63;
    const int g    = lane >> 4;          // frame-PAIR group within wave
    const int s    = lane & 15;
    const int wf0  = (blockIdx.x * 2 + wave) * 8;   // 8 frames per wave
    const int fA   = wf0 + 2 * g;
    const int fB   = fA + 1;

    __shared__ __align__(16) v2f s_x[2][4][ROWP];
    __shared__ float s_win[161];
    __shared__ v2f  s_a[2][4][16];

    // Hann window: each wave writes ALL entries (identical values -> benign
    // race; own-wave writes are ordered before own-wave reads, no barrier).
    {
        const float kW = 6.2831853071795864769f / 159.0f;
        for (int j = lane; j < 161; j += 64) {
            s_win[j] = (j < 160) ? 0.5f - 0.5f * __cosf(kW * (float)j) : 0.0f;
        }
    }
    // Zero front pads (12 pairs x 4 rows) and tail pad (1 pair x 4 rows).
    if (lane < 48) { int gr = lane / 12, j = lane % 12; s_x[wave][gr][j] = splat2(0.f); }
    if (lane < 4)  s_x[wave][lane][172] = splat2(0.f);

    // Stage: coalesced float4 per frame, written pair-interleaved as 2x b128.
    {
        const float* pAg = pcm + (size_t)fA * FRAME;
        const float* pBg = pcm + (size_t)fB * FRAME;
#pragma unroll
        for (int c = 0; c < 3; ++c) {
            int p = 4 * s + 64 * c;
            if (p < FRAME) {
                float4 a4 = *(const float4*)(pAg + p);
                float4 b4 = *(const float4*)(pBg + p);
                float4* dst = (float4*)&s_x[wave][g][12 + p];   // 16B aligned
                dst[0] = make_float4(a4.x, b4.x, a4.y, b4.y);
                dst[1] = make_float4(a4.z, b4.z, a4.w, b4.w);
            }
        }
    }
    __builtin_amdgcn_wave_barrier();

    const v2f* X = &s_x[wave][g][12];    // X[p] = {xA[p], xB[p]}, p in [-12, 160]
    const int p0 = s * EPL;

    // Windowed products; b[p]=xw[p], f[p]=xw[p+1]; position 159 zero invariant
    // (X[160] = 0 via tail pad AND win[160] = 0).
    v2f F[EPL], B[EPL];
    {
        v2f pr[EPL + 1];
#pragma unroll
        for (int j = 0; j <= EPL; ++j)
            pr[j] = X[p0 + j] * s_win[p0 + j];
#pragma unroll
        for (int t = 0; t < EPL; ++t) { F[t] = pr[t + 1]; B[t] = pr[t]; }
    }
    if (s == 15) B[EPL - 1] = splat2(0.f);
    v2f dpF = splat2(0.f), dpB = splat2(0.f);
#pragma unroll
    for (int t = 0; t < EPL; ++t) {
        dpF = pkfma(F[t], F[t], dpF);
        dpB = pkfma(B[t], B[t], dpB);
    }
    v2f den = rowsum16v(dpF + dpB);

    v2f a  = (s == 0) ? splat2(1.f) : splat2(0.f);
    v2f ar = (s == 1) ? splat2(1.f) : splat2(0.f);
    v2f cp = splat2(0.f), dsc = splat2(0.f);

#pragma unroll
    for (int i = 0; i < ORDER; ++i) {
        v2f q0 = splat2(0.f), q1 = splat2(0.f);
#pragma unroll
        for (int t = 0; t < EPL; t += 2) {
            q0 = pkfma(F[t],     B[t],     q0);
            q1 = pkfma(F[t + 1], B[t + 1], q1);
        }
        v2f num = rowsum16v(q0 + q1);
        if (i > 0) den = dsc - rowsum16v(cp);
        v2f r;
        r.x = -2.0f * num.x * __builtin_amdgcn_rcpf(den.x);
        r.y = -2.0f * num.y * __builtin_amdgcn_rcpf(den.y);

        // a[:i+2] += r*a[:i+2][::-1]:  a'=a+r*ar ; ar'=(ar+r*a)>>1 lane
        v2f an  = pkfma(r, ar, a);
        v2f arn = pkfma(r, a, ar);
        a = an;
        ar.x = dppf<0x111>(arn.x);       // row_shr:1, lane0 <- 0
        ar.y = dppf<0x111>(arn.y);

        // In-place lattice update (each pk op serves BOTH frames).
#pragma unroll
        for (int t = 0; t < EPL; ++t) {
            v2f fo = F[t];
            F[t] = pkfma(r, B[t], fo);
            B[t] = pkfma(r, fo, B[t]);
        }

        const int pe = 158 - i;          // compile-time (full unroll)
        const int SL = pe / EPL, SS = pe % EPL;
        v2f fe = (s == 0)  ? F[0]  : splat2(0.f);
        v2f be = (s == SL) ? B[SS] : splat2(0.f);
        cp  = pkfma(fe, fe, be * be);
        dsc = pkfma(-(r * r), den, den); // (1-r^2)*den

        // f = f'[1:]  (row_shl:1; lane15 -> 0 keeps invariant)
        v2f up;
        up.x = dppf<0x101>(F[0].x);
        up.y = dppf<0x101>(F[0].y);
#pragma unroll
        for (int t = 0; t < EPL - 1; ++t) F[t] = F[t + 1];
        F[EPL - 1] = up;
        if (s == SL) B[SS] = splat2(0.f);
    }

    // Broadcast packed a[0..12] within the group via same-wave LDS bounce.
    s_a[wave][g][s] = a;
    __builtin_amdgcn_wave_barrier();
    v2f ak[ORDER + 1];
#pragma unroll
    for (int k = 0; k <= ORDER; ++k) ak[k] = s_a[wave][g][k];

    // FIR window straight from pair-interleaved LDS (front pad = zero history).
    v2f Xw[EPL + ORDER];
#pragma unroll
    for (int j = 0; j < EPL + ORDER; ++j) Xw[j] = X[p0 - ORDER + j];

    const float alpha = alpha_p[0];
    v2f ac;
    ac.x = alpha * (2.0f * (float)bits[fA] - 1.0f);
    ac.y = alpha * (2.0f * (float)bits[fB] - 1.0f);

    float* oA = out + (size_t)fA * FRAME + p0;
    float* oB = out + (size_t)fB * FRAME + p0;
#pragma unroll
    for (int t = 0; t < EPL; t += 2) {
        v2f acc0 = splat2(0.f), acc1 = splat2(0.f);
#pragma unroll
        for (int k = 0; k <= ORDER; ++k) {
            acc0 = pkfma(ak[k], Xw[ORDER + t - k],     acc0);
            acc1 = pkfma(ak[k], Xw[ORDER + t + 1 - k], acc1);
        }
        v2f r0 = pkfma(ac, acc0, Xw[ORDER + t]);
        v2f r1 = pkfma(ac, acc1, Xw[ORDER + t + 1]);
        *(float2*)(oA + t) = make_float2(r0.x, r1.x);
        *(float2*)(oB + t) = make_float2(r0.y, r1.y);
    }
}

extern "C" void kernel_launch(void* const* d_in, const int* in_sizes, int n_in,
                              void* d_out, int out_size, void* d_ws, size_t ws_size,
                              hipStream_t stream) {
    const int*   bits  = (const int*)d_in[0];
    const float* pcm   = (const float*)d_in[1];
    const float* alpha = (const float*)d_in[2];
    float*       out   = (float*)d_out;

    // 61440 frames; 16 per block (2 waves x 4 groups x 2 packed frames).
    dim3 grid(NFRAMES / 16), block(128);
    hipLaunchKernelGGL(ResidualEmbedding_70798240907390_kernel, grid, block, 0, stream,
                       bits, pcm, alpha, out);
}